// Round 1
// baseline (392.239 us; speedup 1.0000x reference)
//
#include <hip/hip_runtime.h>
#include <hip/hip_bf16.h>
#include <math.h>

#define DD 64

__device__ __forceinline__ float fsig(float x) { return 1.0f / (1.0f + __expf(-x)); }
__device__ __forceinline__ float fsilu(float x) { return x * fsig(x); }

// qe = silu(points @ W1 + b1) @ W2 + b2      [N, 64]
__global__ __launch_bounds__(DD) void k_coord(
    const float* __restrict__ coords, const float* __restrict__ W1,
    const float* __restrict__ b1, const float* __restrict__ W2,
    const float* __restrict__ b2, float* __restrict__ qe, int N) {
  int n = blockIdx.x;
  int k = threadIdx.x;
  __shared__ float h[DD];
  float px = coords[n * 3 + 0], py = coords[n * 3 + 1], pz = coords[n * 3 + 2];
  float t = px * W1[k] + py * W1[DD + k] + pz * W1[2 * DD + k] + b1[k];
  h[k] = fsilu(t);
  __syncthreads();
  float q = b2[k];
#pragma unroll 8
  for (int j = 0; j < DD; j++) q += h[j] * W2[j * DD + k];
  qe[n * DD + k] = q;
}

// sg[n] = sigmoid(4 * min_r(|p_n - rpos_r| - rrad_r))   (step-invariant)
__global__ __launch_bounds__(256) void k_sdf(
    const float* __restrict__ rpos, const float* __restrict__ rrad,
    const float* __restrict__ coords, float* __restrict__ sg_out, int N, int R) {
  __shared__ float rp[512 * 3];
  __shared__ float rr[512];
  for (int i = threadIdx.x; i < R * 3; i += blockDim.x) rp[i] = rpos[i];
  for (int i = threadIdx.x; i < R; i += blockDim.x) rr[i] = rrad[i];
  __syncthreads();
  int n = blockIdx.x * blockDim.x + threadIdx.x;
  if (n >= N) return;
  float px = coords[n * 3], py = coords[n * 3 + 1], pz = coords[n * 3 + 2];
  float mn = 1e30f;
  for (int r = 0; r < R; r++) {
    float dx = px - rp[r * 3], dy = py - rp[r * 3 + 1], dz = pz - rp[r * 3 + 2];
    float d = sqrtf(dx * dx + dy * dy + dz * dz) - rr[r];
    mn = fminf(mn, d);
  }
  sg_out[n] = fsig(4.0f * mn);
}

// Per n (block of 256 = M threads): logits -> softmax -> rw ; mc = rw@mem ; qe += 0.5*mc
__global__ __launch_bounds__(256) void k_attn(
    const float* __restrict__ qe_in, const float* __restrict__ keys,
    const float* __restrict__ mem, float* __restrict__ rw_out,
    float* __restrict__ mc_out, float* __restrict__ qe_io, int N, int M) {
  int n = blockIdx.x;
  int t = threadIdx.x;  // t == m index, M == 256
  __shared__ float qs[DD];
  __shared__ float red[256];
  __shared__ float rws[256];
  __shared__ float part[4][DD];
  if (t < DD) qs[t] = qe_in[n * DD + t];
  __syncthreads();
  float logit = 0.f;
#pragma unroll 8
  for (int j = 0; j < DD; j++) logit += qs[j] * keys[t * DD + j];
  logit *= 0.125f;  // 1/sqrt(64)
  red[t] = logit;
  __syncthreads();
  for (int s = 128; s > 0; s >>= 1) {
    if (t < s) red[t] = fmaxf(red[t], red[t + s]);
    __syncthreads();
  }
  float mx = red[0];
  __syncthreads();
  float e = __expf(logit - mx);
  red[t] = e;
  __syncthreads();
  for (int s = 128; s > 0; s >>= 1) {
    if (t < s) red[t] += red[t + s];
    __syncthreads();
  }
  float rw = e / red[0];
  rw_out[n * M + t] = rw;
  rws[t] = rw;
  __syncthreads();
  int g = t >> 6, k = t & 63;
  float acc = 0.f;
  for (int mm = 0; mm < 64; mm++) {
    int m2 = g * 64 + mm;
    acc += rws[m2] * mem[m2 * DD + k];
  }
  part[g][k] = acc;
  __syncthreads();
  if (t < DD) {
    float mc = part[0][t] + part[1][t] + part[2][t] + part[3][t];
    mc_out[n * DD + t] = mc;
    qe_io[n * DD + t] = qs[t] + 0.5f * mc;
  }
}

// Ag[n] = mc[n]@Wg1[0:64] + sg[n]*Wg1[129] + bg1 ; Au likewise (Wu1)
// Bg[m] = mem[m]@Wg1[64:128] ; Bu likewise
__global__ __launch_bounds__(DD) void k_ab(
    const float* __restrict__ mc, const float* __restrict__ sg,
    const float* __restrict__ mem, const float* __restrict__ Wg1,
    const float* __restrict__ bg1, const float* __restrict__ Wu1,
    const float* __restrict__ bu1, float* __restrict__ Ag, float* __restrict__ Au,
    float* __restrict__ Bg, float* __restrict__ Bu, int N, int M) {
  int b = blockIdx.x;
  int k = threadIdx.x;  // 64 threads
  __shared__ float row[DD];
  if (b < N) {
    int n = b;
    row[k] = mc[n * DD + k];
    __syncthreads();
    float sgn = sg[n];
    float ag = bg1[k] + sgn * Wg1[129 * DD + k];
    float au = bu1[k] + sgn * Wu1[129 * DD + k];
#pragma unroll 8
    for (int j = 0; j < DD; j++) {
      float r = row[j];
      ag += r * Wg1[j * DD + k];
      au += r * Wu1[j * DD + k];
    }
    Ag[n * DD + k] = ag;
    Au[n * DD + k] = au;
  } else {
    int m = b - N;
    row[k] = mem[m * DD + k];
    __syncthreads();
    float bg = 0.f, bu = 0.f;
#pragma unroll 8
    for (int j = 0; j < DD; j++) {
      float r = row[j];
      bg += r * Wg1[(DD + j) * DD + k];
      bu += r * Wu1[(DD + j) * DD + k];
    }
    Bg[m * DD + k] = bg;
    Bu[m * DD + k] = bu;
  }
}

// Main pair loop: one wave per n, lane = k. Accumulate per-m gate sum and Su sum over an n-chunk.
__global__ __launch_bounds__(256) void k_write(
    const float* __restrict__ rw, const float* __restrict__ Ag,
    const float* __restrict__ Au, const float* __restrict__ Bg,
    const float* __restrict__ Bu, const float* __restrict__ Wg1,
    const float* __restrict__ Wu1, const float* __restrict__ Wg2,
    const float* __restrict__ bg2, float* __restrict__ gate_part,
    float* __restrict__ su_part, int N, int M, int NCH) {
  int m = blockIdx.x / NCH;
  int c = blockIdx.x % NCH;
  int wave = threadIdx.x >> 6, k = threadIdx.x & 63;
  float bgk = Bg[m * DD + k], buk = Bu[m * DD + k];
  float wg1r = Wg1[128 * DD + k], wu1r = Wu1[128 * DD + k];
  float wg2k = Wg2[k], bg2v = bg2[0];
  float su = 0.f, gsum = 0.f;
  int n0 = c * 256 + wave * 64;
  for (int i = 0; i < 64; i++) {
    int n = n0 + i;
    float rwv = rw[n * M + m];
    float ag = Ag[n * DD + k], au = Au[n * DD + k];
    float tg = ag + bgk + rwv * wg1r;
    float d = fsilu(tg) * wg2k;
    d += __shfl_xor(d, 32, 64);
    d += __shfl_xor(d, 16, 64);
    d += __shfl_xor(d, 8, 64);
    d += __shfl_xor(d, 4, 64);
    d += __shfl_xor(d, 2, 64);
    d += __shfl_xor(d, 1, 64);
    gsum += fsig(d + bg2v);  // identical across lanes (butterfly)
    float tu = au + buk + rwv * wu1r;
    su += fsilu(tu);
  }
  __shared__ float su_s[4][DD];
  __shared__ float g_s[4];
  su_s[wave][k] = su;
  if (k == 0) g_s[wave] = gsum;
  __syncthreads();
  if (threadIdx.x < DD) {
    float s = su_s[0][k] + su_s[1][k] + su_s[2][k] + su_s[3][k];
    su_part[(m * NCH + c) * DD + k] = s;
    if (k == 0) gate_part[m * NCH + c] = g_s[0] + g_s[1] + g_s[2] + g_s[3];
  }
}

// Final per-m reduce: gate mean, delta = (Su/N)@Wu2 + bu2, mem2 = mem + gate*delta
__global__ __launch_bounds__(DD) void k_reduce(
    const float* __restrict__ gate_part, const float* __restrict__ su_part,
    const float* __restrict__ Wu2, const float* __restrict__ bu2,
    const float* __restrict__ mem_in, float* __restrict__ mem_out,
    float* __restrict__ gate_out, int N, int M, int NCH) {
  int m = blockIdx.x;
  int k = threadIdx.x;
  __shared__ float su_s[DD];
  __shared__ float gmean;
  float s = 0.f;
  for (int c = 0; c < NCH; c++) s += su_part[(m * NCH + c) * DD + k];
  su_s[k] = s / (float)N;
  if (k == 0) {
    float g = 0.f;
    for (int c = 0; c < NCH; c++) g += gate_part[m * NCH + c];
    gmean = g / (float)N;
  }
  __syncthreads();
  float delta = bu2[k];
#pragma unroll 8
  for (int j = 0; j < DD; j++) delta += su_s[j] * Wu2[j * DD + k];
  float gm = gmean;
  mem_out[m * DD + k] = mem_in[m * DD + k] + gm * delta;
  if (k == 0) gate_out[m] = gm;
}

extern "C" void kernel_launch(void* const* d_in, const int* in_sizes, int n_in,
                              void* d_out, int out_size, void* d_ws, size_t ws_size,
                              hipStream_t stream) {
  const float* coords = (const float*)d_in[0];
  const float* memory_slots = (const float*)d_in[1];
  const float* anchor_keys = (const float*)d_in[2];
  const float* rpos = (const float*)d_in[3];
  const float* rrad = (const float*)d_in[4];
  const float* W1 = (const float*)d_in[5];
  const float* b1 = (const float*)d_in[6];
  const float* W2 = (const float*)d_in[7];
  const float* b2 = (const float*)d_in[8];
  const float* Wg1 = (const float*)d_in[9];
  const float* bg1 = (const float*)d_in[10];
  const float* Wg2 = (const float*)d_in[11];
  const float* bg2 = (const float*)d_in[12];
  const float* Wu1 = (const float*)d_in[13];
  const float* bu1 = (const float*)d_in[14];
  const float* Wu2 = (const float*)d_in[15];
  const float* bu2 = (const float*)d_in[16];

  const int N = in_sizes[0] / 3;   // 4096
  const int M = in_sizes[1] / DD;  // 256
  const int R = in_sizes[4];       // 512
  const int NCH = N / 256;         // 16

  // d_out layout: mc[N*D] | rw[N*M] | gate[M] | sg[N] | mem[M*D]
  float* out = (float*)d_out;
  float* out_mc = out;
  float* out_rw = out_mc + (size_t)N * DD;
  float* out_gate = out_rw + (size_t)N * M;
  float* out_sg = out_gate + M;
  float* out_mem = out_sg + N;

  // workspace layout
  float* ws = (float*)d_ws;
  float* qe = ws;                    ws += (size_t)N * DD;
  float* Ag = ws;                    ws += (size_t)N * DD;
  float* Au = ws;                    ws += (size_t)N * DD;
  float* Bg = ws;                    ws += (size_t)M * DD;
  float* Bu = ws;                    ws += (size_t)M * DD;
  float* gate_part = ws;             ws += (size_t)M * NCH;
  float* su_part = ws;               ws += (size_t)M * NCH * DD;

  k_coord<<<N, DD, 0, stream>>>(coords, W1, b1, W2, b2, qe, N);
  k_sdf<<<(N + 255) / 256, 256, 0, stream>>>(rpos, rrad, coords, out_sg, N, R);

  const float* mem_cur = memory_slots;
  for (int step = 0; step < 2; step++) {
    k_attn<<<N, 256, 0, stream>>>(qe, anchor_keys, mem_cur, out_rw, out_mc, qe, N, M);
    k_ab<<<N + M, DD, 0, stream>>>(out_mc, out_sg, mem_cur, Wg1, bg1, Wu1, bu1,
                                   Ag, Au, Bg, Bu, N, M);
    k_write<<<M * NCH, 256, 0, stream>>>(out_rw, Ag, Au, Bg, Bu, Wg1, Wu1, Wg2,
                                         bg2, gate_part, su_part, N, M, NCH);
    k_reduce<<<M, DD, 0, stream>>>(gate_part, su_part, Wu2, bu2, mem_cur,
                                   out_mem, out_gate, N, M, NCH);
    mem_cur = out_mem;
  }
}

// Round 2
// 225.086 us; speedup vs baseline: 1.7426x; 1.7426x over previous
//
#include <hip/hip_runtime.h>
#include <hip/hip_bf16.h>
#include <math.h>

#define DD 64

__device__ __forceinline__ float frcp(float x) { return __builtin_amdgcn_rcpf(x); }
__device__ __forceinline__ float fsig(float x) { return frcp(1.0f + __expf(-x)); }
__device__ __forceinline__ float fsilu(float x) { return x * fsig(x); }

// qe = silu(points @ W1 + b1) @ W2 + b2      [N, 64]
__global__ __launch_bounds__(DD) void k_coord(
    const float* __restrict__ coords, const float* __restrict__ W1,
    const float* __restrict__ b1, const float* __restrict__ W2,
    const float* __restrict__ b2, float* __restrict__ qe, int N) {
  int n = blockIdx.x;
  int k = threadIdx.x;
  __shared__ float h[DD];
  float px = coords[n * 3 + 0], py = coords[n * 3 + 1], pz = coords[n * 3 + 2];
  float t = px * W1[k] + py * W1[DD + k] + pz * W1[2 * DD + k] + b1[k];
  h[k] = fsilu(t);
  __syncthreads();
  float q = b2[k];
#pragma unroll 8
  for (int j = 0; j < DD; j++) q += h[j] * W2[j * DD + k];
  qe[n * DD + k] = q;
}

// keysT[j][m] = keys[m][j]  (one-time transpose for coalesced logit loads)
__global__ __launch_bounds__(256) void k_prep(
    const float* __restrict__ keys, float* __restrict__ keysT, int M) {
  int j = blockIdx.x;   // 0..63
  int t = threadIdx.x;  // 0..255 (m)
  keysT[j * M + t] = keys[t * DD + j];
}

// sg[n] = sigmoid(4 * min_r(|p_n - rpos_r| - rrad_r))   (step-invariant)
__global__ __launch_bounds__(256) void k_sdf(
    const float* __restrict__ rpos, const float* __restrict__ rrad,
    const float* __restrict__ coords, float* __restrict__ sg_out, int N, int R) {
  __shared__ float rp[512 * 3];
  __shared__ float rr[512];
  for (int i = threadIdx.x; i < R * 3; i += blockDim.x) rp[i] = rpos[i];
  for (int i = threadIdx.x; i < R; i += blockDim.x) rr[i] = rrad[i];
  __syncthreads();
  int n = blockIdx.x * blockDim.x + threadIdx.x;
  if (n >= N) return;
  float px = coords[n * 3], py = coords[n * 3 + 1], pz = coords[n * 3 + 2];
  float mn = 1e30f;
  for (int r = 0; r < R; r++) {
    float dx = px - rp[r * 3], dy = py - rp[r * 3 + 1], dz = pz - rp[r * 3 + 2];
    float d = sqrtf(dx * dx + dy * dy + dz * dz) - rr[r];
    mn = fminf(mn, d);
  }
  sg_out[n] = fsig(4.0f * mn);
}

// Per n: logits -> softmax -> rw ; mc = rw@mem ; qe += 0.5*mc ;
// fused A-projection: Ag (transposed/packed) and Au rows for this n.
__global__ __launch_bounds__(256) void k_attn(
    const float* __restrict__ qe_in, const float* __restrict__ keysT,
    const float* __restrict__ mem, const float* __restrict__ sg,
    const float* __restrict__ Wg1, const float* __restrict__ bg1,
    const float* __restrict__ Wu1, const float* __restrict__ bu1,
    float* __restrict__ rw_out, float* __restrict__ mc_out,
    float* __restrict__ qe_io, float* __restrict__ AgT4,
    float* __restrict__ Au, int N, int M) {
  int n = blockIdx.x;
  int t = threadIdx.x;  // t == m index, M == 256
  __shared__ float qs[DD];
  __shared__ float red[8];
  __shared__ float rws[256];
  __shared__ float part[4][DD];
  __shared__ float mcs[DD];
  if (t < DD) qs[t] = qe_in[n * DD + t];
  __syncthreads();
  float logit = 0.f;
#pragma unroll 8
  for (int j = 0; j < DD; j++) logit += qs[j] * keysT[j * M + t];
  logit *= 0.125f;  // 1/sqrt(64)
  int wv = t >> 6, ln = t & 63;
  // wave max
  float mx = logit;
  mx = fmaxf(mx, __shfl_xor(mx, 32, 64));
  mx = fmaxf(mx, __shfl_xor(mx, 16, 64));
  mx = fmaxf(mx, __shfl_xor(mx, 8, 64));
  mx = fmaxf(mx, __shfl_xor(mx, 4, 64));
  mx = fmaxf(mx, __shfl_xor(mx, 2, 64));
  mx = fmaxf(mx, __shfl_xor(mx, 1, 64));
  if (ln == 0) red[wv] = mx;
  __syncthreads();
  mx = fmaxf(fmaxf(red[0], red[1]), fmaxf(red[2], red[3]));
  float e = __expf(logit - mx);
  float sm = e;
  sm += __shfl_xor(sm, 32, 64);
  sm += __shfl_xor(sm, 16, 64);
  sm += __shfl_xor(sm, 8, 64);
  sm += __shfl_xor(sm, 4, 64);
  sm += __shfl_xor(sm, 2, 64);
  sm += __shfl_xor(sm, 1, 64);
  if (ln == 0) red[4 + wv] = sm;
  __syncthreads();
  float tot = red[4] + red[5] + red[6] + red[7];
  float rwv = e * frcp(tot);
  rw_out[n * M + t] = rwv;
  rws[t] = rwv;
  __syncthreads();
  // mc = rw @ mem
  float acc = 0.f;
#pragma unroll 8
  for (int mm = 0; mm < 64; mm++) {
    int m2 = wv * 64 + mm;
    acc += rws[m2] * mem[m2 * DD + ln];
  }
  part[wv][ln] = acc;
  __syncthreads();
  if (t < DD) {
    float mc = part[0][t] + part[1][t] + part[2][t] + part[3][t];
    mc_out[n * DD + t] = mc;
    qe_io[n * DD + t] = qs[t] + 0.5f * mc;
    mcs[t] = mc;
  }
  __syncthreads();
  // A-projection: wave0 -> Ag (k=t), wave1 -> Au (k=t-64)
  if (t < 128) {
    int k = t & 63;
    const float* W = (t < DD) ? Wg1 : Wu1;
    const float* bb = (t < DD) ? bg1 : bu1;
    float sgn = sg[n];
    float a = bb[k] + sgn * W[129 * DD + k];
#pragma unroll 8
    for (int j = 0; j < DD; j++) a += mcs[j] * W[j * DD + k];
    if (t < DD)
      AgT4[((size_t)(k >> 2) * N + n) * 4 + (k & 3)] = a;
    else
      Au[(size_t)n * DD + k] = a;
  }
}

// Bg[m] = mem[m]@Wg1[64:128] ; Bu[m] = mem[m]@Wu1[64:128]
__global__ __launch_bounds__(128) void k_b(
    const float* __restrict__ mem, const float* __restrict__ Wg1,
    const float* __restrict__ Wu1, float* __restrict__ Bg,
    float* __restrict__ Bu, int M) {
  int m = blockIdx.x;
  int t = threadIdx.x;
  __shared__ float row[DD];
  if (t < DD) row[t] = mem[m * DD + t];
  __syncthreads();
  int k = t & 63;
  const float* W = (t < DD) ? Wg1 : Wu1;
  float b = 0.f;
#pragma unroll 8
  for (int j = 0; j < DD; j++) b += row[j] * W[(DD + j) * DD + k];
  if (t < DD) Bg[m * DD + k] = b;
  else Bu[m * DD + k] = b;
}

// Main pair loop. Block = (m, c): 4 waves, wave handles 64 n's.
// Path G: lane=n, loop k (per-k constants are scalar loads). Path U: lane=k, loop n.
__global__ __launch_bounds__(256) void k_write(
    const float* __restrict__ rw, const float* __restrict__ AgT4,
    const float* __restrict__ Au, const float* __restrict__ Bg,
    const float* __restrict__ Bu, const float* __restrict__ Wg1,
    const float* __restrict__ Wu1, const float* __restrict__ Wg2,
    const float* __restrict__ bg2, float* __restrict__ gate_part,
    float* __restrict__ su_part, int N, int M, int NCH) {
  int m = blockIdx.x;
  int c = blockIdx.y;
  int wave = threadIdx.x >> 6, lane = threadIdx.x & 63;
  int n0 = __builtin_amdgcn_readfirstlane(c * 256 + wave * 64);

  // ---- path G: lane = n offset ----
  float rwl = rw[(size_t)(n0 + lane) * M + m];  // per-lane gather, reused below
  float g_acc = 0.f;
#pragma unroll 4
  for (int k4 = 0; k4 < 16; k4++) {
    const float4 ag4 = *reinterpret_cast<const float4*>(
        &AgT4[((size_t)k4 * N + n0 + lane) * 4]);
    float bg0 = Bg[m * DD + k4 * 4 + 0];
    float bg1v = Bg[m * DD + k4 * 4 + 1];
    float bg2v_ = Bg[m * DD + k4 * 4 + 2];
    float bg3 = Bg[m * DD + k4 * 4 + 3];
    float wr0 = Wg1[128 * DD + k4 * 4 + 0];
    float wr1 = Wg1[128 * DD + k4 * 4 + 1];
    float wr2 = Wg1[128 * DD + k4 * 4 + 2];
    float wr3 = Wg1[128 * DD + k4 * 4 + 3];
    float w20 = Wg2[k4 * 4 + 0];
    float w21 = Wg2[k4 * 4 + 1];
    float w22 = Wg2[k4 * 4 + 2];
    float w23 = Wg2[k4 * 4 + 3];
    float tg0 = ag4.x + bg0 + rwl * wr0;
    float tg1 = ag4.y + bg1v + rwl * wr1;
    float tg2 = ag4.z + bg2v_ + rwl * wr2;
    float tg3 = ag4.w + bg3 + rwl * wr3;
    g_acc += fsilu(tg0) * w20;
    g_acc += fsilu(tg1) * w21;
    g_acc += fsilu(tg2) * w22;
    g_acc += fsilu(tg3) * w23;
  }
  float gate_n = fsig(g_acc + bg2[0]);  // gate for n = n0+lane
  // one butterfly per wave (not per pair)
  gate_n += __shfl_xor(gate_n, 32, 64);
  gate_n += __shfl_xor(gate_n, 16, 64);
  gate_n += __shfl_xor(gate_n, 8, 64);
  gate_n += __shfl_xor(gate_n, 4, 64);
  gate_n += __shfl_xor(gate_n, 2, 64);
  gate_n += __shfl_xor(gate_n, 1, 64);

  // ---- path U: lane = k ----
  float buk = Bu[m * DD + lane];
  float wu1r = Wu1[128 * DD + lane];
  float su = 0.f;
  const float* Aup = Au + (size_t)n0 * DD + lane;
#pragma unroll 8
  for (int i = 0; i < 64; i++) {
    float rwv = rw[(size_t)(n0 + i) * M + m];  // wave-uniform -> scalar load
    float au = Aup[(size_t)i * DD];
    float tu = au + buk + rwv * wu1r;
    su += fsilu(tu);
  }

  __shared__ float su_s[4][DD];
  __shared__ float g_s[4];
  su_s[wave][lane] = su;
  if (lane == 0) g_s[wave] = gate_n;
  __syncthreads();
  if (threadIdx.x < DD) {
    int k = threadIdx.x;
    float s = su_s[0][k] + su_s[1][k] + su_s[2][k] + su_s[3][k];
    su_part[((size_t)m * NCH + c) * DD + k] = s;
    if (k == 0) gate_part[m * NCH + c] = g_s[0] + g_s[1] + g_s[2] + g_s[3];
  }
}

// Final per-m reduce: gate mean, delta = (Su/N)@Wu2 + bu2, mem2 = mem + gate*delta
__global__ __launch_bounds__(DD) void k_reduce(
    const float* __restrict__ gate_part, const float* __restrict__ su_part,
    const float* __restrict__ Wu2, const float* __restrict__ bu2,
    const float* __restrict__ mem_in, float* __restrict__ mem_out,
    float* __restrict__ gate_out, int N, int M, int NCH) {
  int m = blockIdx.x;
  int k = threadIdx.x;
  __shared__ float su_s[DD];
  __shared__ float gmean;
  float invN = frcp((float)N);  // N is a power of two -> exact
  float s = 0.f;
  for (int c = 0; c < NCH; c++) s += su_part[((size_t)m * NCH + c) * DD + k];
  su_s[k] = s * invN;
  if (k == 0) {
    float g = 0.f;
    for (int c = 0; c < NCH; c++) g += gate_part[m * NCH + c];
    gmean = g * invN;
  }
  __syncthreads();
  float delta = bu2[k];
#pragma unroll 8
  for (int j = 0; j < DD; j++) delta += su_s[j] * Wu2[j * DD + k];
  float gm = gmean;
  mem_out[m * DD + k] = mem_in[m * DD + k] + gm * delta;
  if (k == 0) gate_out[m] = gm;
}

extern "C" void kernel_launch(void* const* d_in, const int* in_sizes, int n_in,
                              void* d_out, int out_size, void* d_ws, size_t ws_size,
                              hipStream_t stream) {
  const float* coords = (const float*)d_in[0];
  const float* memory_slots = (const float*)d_in[1];
  const float* anchor_keys = (const float*)d_in[2];
  const float* rpos = (const float*)d_in[3];
  const float* rrad = (const float*)d_in[4];
  const float* W1 = (const float*)d_in[5];
  const float* b1 = (const float*)d_in[6];
  const float* W2 = (const float*)d_in[7];
  const float* b2 = (const float*)d_in[8];
  const float* Wg1 = (const float*)d_in[9];
  const float* bg1 = (const float*)d_in[10];
  const float* bg2 = (const float*)d_in[12];
  const float* Wg2 = (const float*)d_in[11];
  const float* Wu1 = (const float*)d_in[13];
  const float* bu1 = (const float*)d_in[14];
  const float* Wu2 = (const float*)d_in[15];
  const float* bu2 = (const float*)d_in[16];

  const int N = in_sizes[0] / 3;   // 4096
  const int M = in_sizes[1] / DD;  // 256
  const int R = in_sizes[4];       // 512
  const int NCH = N / 256;         // 16

  // d_out layout: mc[N*D] | rw[N*M] | gate[M] | sg[N] | mem[M*D]
  float* out = (float*)d_out;
  float* out_mc = out;
  float* out_rw = out_mc + (size_t)N * DD;
  float* out_gate = out_rw + (size_t)N * M;
  float* out_sg = out_gate + M;
  float* out_mem = out_sg + N;

  // workspace layout
  float* ws = (float*)d_ws;
  float* qe = ws;        ws += (size_t)N * DD;
  float* AgT4 = ws;      ws += (size_t)N * DD;
  float* Au = ws;        ws += (size_t)N * DD;
  float* keysT = ws;     ws += (size_t)DD * M;
  float* Bg = ws;        ws += (size_t)M * DD;
  float* Bu = ws;        ws += (size_t)M * DD;
  float* gate_part = ws; ws += (size_t)M * NCH;
  float* su_part = ws;   ws += (size_t)M * NCH * DD;

  k_coord<<<N, DD, 0, stream>>>(coords, W1, b1, W2, b2, qe, N);
  k_prep<<<DD, M, 0, stream>>>(anchor_keys, keysT, M);
  k_sdf<<<(N + 255) / 256, 256, 0, stream>>>(rpos, rrad, coords, out_sg, N, R);

  const float* mem_cur = memory_slots;
  for (int step = 0; step < 2; step++) {
    k_attn<<<N, 256, 0, stream>>>(qe, keysT, mem_cur, out_sg, Wg1, bg1, Wu1, bu1,
                                  out_rw, out_mc, qe, AgT4, Au, N, M);
    k_b<<<M, 128, 0, stream>>>(mem_cur, Wg1, Wu1, Bg, Bu, M);
    k_write<<<dim3(M, NCH), 256, 0, stream>>>(out_rw, AgT4, Au, Bg, Bu, Wg1, Wu1,
                                              Wg2, bg2, gate_part, su_part, N, M, NCH);
    k_reduce<<<M, DD, 0, stream>>>(gate_part, su_part, Wu2, bu2, mem_cur,
                                   out_mem, out_gate, N, M, NCH);
    mem_cur = out_mem;
  }
}

// Round 3
// 176.834 us; speedup vs baseline: 2.2181x; 1.2729x over previous
//
#include <hip/hip_runtime.h>
#include <hip/hip_bf16.h>
#include <math.h>

#define DD 64

__device__ __forceinline__ float frcp(float x) { return __builtin_amdgcn_rcpf(x); }
__device__ __forceinline__ float fsig(float x) { return frcp(1.0f + __expf(-x)); }
__device__ __forceinline__ float fsilu(float x) { return x * fsig(x); }

// qe = silu(points @ W1 + b1) @ W2 + b2      [N, 64]
__global__ __launch_bounds__(DD) void k_coord(
    const float* __restrict__ coords, const float* __restrict__ W1,
    const float* __restrict__ b1, const float* __restrict__ W2,
    const float* __restrict__ b2, float* __restrict__ qe, int N) {
  int n = blockIdx.x;
  int k = threadIdx.x;
  __shared__ float h[DD];
  float px = coords[n * 3 + 0], py = coords[n * 3 + 1], pz = coords[n * 3 + 2];
  float t = px * W1[k] + py * W1[DD + k] + pz * W1[2 * DD + k] + b1[k];
  h[k] = fsilu(t);
  __syncthreads();
  float q = b2[k];
#pragma unroll 8
  for (int j = 0; j < DD; j++) q += h[j] * W2[j * DD + k];
  qe[n * DD + k] = q;
}

// keysT[j][m] = keys[m][j]  (one-time transpose for coalesced logit loads)
__global__ __launch_bounds__(256) void k_prep(
    const float* __restrict__ keys, float* __restrict__ keysT, int M) {
  int j = blockIdx.x;   // 0..63
  int t = threadIdx.x;  // 0..255 (m)
  keysT[j * M + t] = keys[t * DD + j];
}

// sg[n] = sigmoid(4 * min_r(|p_n - rpos_r| - rrad_r))   (step-invariant)
// One wave per n: lane l covers r = l, l+64, ... ; butterfly min-reduce.
__global__ __launch_bounds__(256) void k_sdf(
    const float* __restrict__ rpos, const float* __restrict__ rrad,
    const float* __restrict__ coords, float* __restrict__ sg_out, int N, int R) {
  int wv = threadIdx.x >> 6, ln = threadIdx.x & 63;
  int n = blockIdx.x * 4 + wv;
  if (n >= N) return;
  float px = coords[n * 3], py = coords[n * 3 + 1], pz = coords[n * 3 + 2];
  float mn = 1e30f;
  for (int r = ln; r < R; r += 64) {
    float dx = px - rpos[r * 3], dy = py - rpos[r * 3 + 1], dz = pz - rpos[r * 3 + 2];
    float d = sqrtf(dx * dx + dy * dy + dz * dz) - rrad[r];
    mn = fminf(mn, d);
  }
  mn = fminf(mn, __shfl_xor(mn, 32, 64));
  mn = fminf(mn, __shfl_xor(mn, 16, 64));
  mn = fminf(mn, __shfl_xor(mn, 8, 64));
  mn = fminf(mn, __shfl_xor(mn, 4, 64));
  mn = fminf(mn, __shfl_xor(mn, 2, 64));
  mn = fminf(mn, __shfl_xor(mn, 1, 64));
  if (ln == 0) sg_out[n] = fsig(4.0f * mn);
}

// Per n: logits -> softmax -> rw ; mc = rw@mem ; qe += 0.5*mc ;
// fused A-projection: Ag (transposed/packed) and Au rows for this n.
__global__ __launch_bounds__(256) void k_attn(
    const float* __restrict__ qe_in, const float* __restrict__ keysT,
    const float* __restrict__ mem, const float* __restrict__ sg,
    const float* __restrict__ Wg1, const float* __restrict__ bg1,
    const float* __restrict__ Wu1, const float* __restrict__ bu1,
    float* __restrict__ rw_out, float* __restrict__ mc_out,
    float* __restrict__ qe_io, float* __restrict__ AgT4,
    float* __restrict__ Au, int N, int M) {
  int n = blockIdx.x;
  int t = threadIdx.x;  // t == m index, M == 256
  __shared__ float qs[DD];
  __shared__ float red[8];
  __shared__ float rws[256];
  __shared__ float part[4][DD];
  __shared__ float mcs[DD];
  if (t < DD) qs[t] = qe_in[n * DD + t];
  __syncthreads();
  float logit = 0.f;
#pragma unroll 8
  for (int j = 0; j < DD; j++) logit += qs[j] * keysT[j * M + t];
  logit *= 0.125f;  // 1/sqrt(64)
  int wv = t >> 6, ln = t & 63;
  // wave max
  float mx = logit;
  mx = fmaxf(mx, __shfl_xor(mx, 32, 64));
  mx = fmaxf(mx, __shfl_xor(mx, 16, 64));
  mx = fmaxf(mx, __shfl_xor(mx, 8, 64));
  mx = fmaxf(mx, __shfl_xor(mx, 4, 64));
  mx = fmaxf(mx, __shfl_xor(mx, 2, 64));
  mx = fmaxf(mx, __shfl_xor(mx, 1, 64));
  if (ln == 0) red[wv] = mx;
  __syncthreads();
  mx = fmaxf(fmaxf(red[0], red[1]), fmaxf(red[2], red[3]));
  float e = __expf(logit - mx);
  float sm = e;
  sm += __shfl_xor(sm, 32, 64);
  sm += __shfl_xor(sm, 16, 64);
  sm += __shfl_xor(sm, 8, 64);
  sm += __shfl_xor(sm, 4, 64);
  sm += __shfl_xor(sm, 2, 64);
  sm += __shfl_xor(sm, 1, 64);
  if (ln == 0) red[4 + wv] = sm;
  __syncthreads();
  float tot = red[4] + red[5] + red[6] + red[7];
  float rwv = e * frcp(tot);
  rw_out[n * M + t] = rwv;
  rws[t] = rwv;
  __syncthreads();
  // mc = rw @ mem
  float acc = 0.f;
#pragma unroll 8
  for (int mm = 0; mm < 64; mm++) {
    int m2 = wv * 64 + mm;
    acc += rws[m2] * mem[m2 * DD + ln];
  }
  part[wv][ln] = acc;
  __syncthreads();
  if (t < DD) {
    float mc = part[0][t] + part[1][t] + part[2][t] + part[3][t];
    mc_out[n * DD + t] = mc;
    qe_io[n * DD + t] = qs[t] + 0.5f * mc;
    mcs[t] = mc;
  }
  __syncthreads();
  // A-projection: wave0 -> Ag (k=t), wave1 -> Au (k=t-64)
  if (t < 128) {
    int k = t & 63;
    const float* W = (t < DD) ? Wg1 : Wu1;
    const float* bb = (t < DD) ? bg1 : bu1;
    float sgn = sg[n];
    float a = bb[k] + sgn * W[129 * DD + k];
#pragma unroll 8
    for (int j = 0; j < DD; j++) a += mcs[j] * W[j * DD + k];
    if (t < DD)
      AgT4[((size_t)(k >> 2) * N + n) * 4 + (k & 3)] = a;
    else
      Au[(size_t)n * DD + k] = a;
  }
}

// Bg[m] = mem[m]@Wg1[64:128] ; Bu[m] = mem[m]@Wu1[64:128]
__global__ __launch_bounds__(128) void k_b(
    const float* __restrict__ mem, const float* __restrict__ Wg1,
    const float* __restrict__ Wu1, float* __restrict__ Bg,
    float* __restrict__ Bu, int M) {
  int m = blockIdx.x;
  int t = threadIdx.x;
  __shared__ float row[DD];
  if (t < DD) row[t] = mem[m * DD + t];
  __syncthreads();
  int k = t & 63;
  const float* W = (t < DD) ? Wg1 : Wu1;
  float b = 0.f;
#pragma unroll 8
  for (int j = 0; j < DD; j++) b += row[j] * W[(DD + j) * DD + k];
  if (t < DD) Bg[m * DD + k] = b;
  else Bu[m * DD + k] = b;
}

// Main pair loop. Block = (m, c): 4 waves, wave handles 64 n's.
// Path G: lane=n, loop k (per-k constants are scalar loads). Path U: lane=k, loop n.
__global__ __launch_bounds__(256) void k_write(
    const float* __restrict__ rw, const float* __restrict__ AgT4,
    const float* __restrict__ Au, const float* __restrict__ Bg,
    const float* __restrict__ Bu, const float* __restrict__ Wg1,
    const float* __restrict__ Wu1, const float* __restrict__ Wg2,
    const float* __restrict__ bg2, float* __restrict__ gate_part,
    float* __restrict__ su_part, int N, int M, int NCH) {
  int m = blockIdx.x;
  int c = blockIdx.y;
  int wave = threadIdx.x >> 6, lane = threadIdx.x & 63;
  int n0 = __builtin_amdgcn_readfirstlane(c * 256 + wave * 64);

  // ---- path G: lane = n offset ----
  float rwl = rw[(size_t)(n0 + lane) * M + m];  // per-lane gather, reused below
  float g_acc = 0.f;
#pragma unroll 4
  for (int k4 = 0; k4 < 16; k4++) {
    const float4 ag4 = *reinterpret_cast<const float4*>(
        &AgT4[((size_t)k4 * N + n0 + lane) * 4]);
    float bg0 = Bg[m * DD + k4 * 4 + 0];
    float bg1v = Bg[m * DD + k4 * 4 + 1];
    float bg2v_ = Bg[m * DD + k4 * 4 + 2];
    float bg3 = Bg[m * DD + k4 * 4 + 3];
    float wr0 = Wg1[128 * DD + k4 * 4 + 0];
    float wr1 = Wg1[128 * DD + k4 * 4 + 1];
    float wr2 = Wg1[128 * DD + k4 * 4 + 2];
    float wr3 = Wg1[128 * DD + k4 * 4 + 3];
    float w20 = Wg2[k4 * 4 + 0];
    float w21 = Wg2[k4 * 4 + 1];
    float w22 = Wg2[k4 * 4 + 2];
    float w23 = Wg2[k4 * 4 + 3];
    float tg0 = ag4.x + bg0 + rwl * wr0;
    float tg1 = ag4.y + bg1v + rwl * wr1;
    float tg2 = ag4.z + bg2v_ + rwl * wr2;
    float tg3 = ag4.w + bg3 + rwl * wr3;
    g_acc += fsilu(tg0) * w20;
    g_acc += fsilu(tg1) * w21;
    g_acc += fsilu(tg2) * w22;
    g_acc += fsilu(tg3) * w23;
  }
  float gate_n = fsig(g_acc + bg2[0]);  // gate for n = n0+lane
  // one butterfly per wave (not per pair)
  gate_n += __shfl_xor(gate_n, 32, 64);
  gate_n += __shfl_xor(gate_n, 16, 64);
  gate_n += __shfl_xor(gate_n, 8, 64);
  gate_n += __shfl_xor(gate_n, 4, 64);
  gate_n += __shfl_xor(gate_n, 2, 64);
  gate_n += __shfl_xor(gate_n, 1, 64);

  // ---- path U: lane = k ----
  float buk = Bu[m * DD + lane];
  float wu1r = Wu1[128 * DD + lane];
  float su = 0.f;
  const float* Aup = Au + (size_t)n0 * DD + lane;
#pragma unroll 8
  for (int i = 0; i < 64; i++) {
    float rwv = rw[(size_t)(n0 + i) * M + m];  // wave-uniform -> scalar load
    float au = Aup[(size_t)i * DD];
    float tu = au + buk + rwv * wu1r;
    su += fsilu(tu);
  }

  __shared__ float su_s[4][DD];
  __shared__ float g_s[4];
  su_s[wave][lane] = su;
  if (lane == 0) g_s[wave] = gate_n;
  __syncthreads();
  if (threadIdx.x < DD) {
    int k = threadIdx.x;
    float s = su_s[0][k] + su_s[1][k] + su_s[2][k] + su_s[3][k];
    su_part[((size_t)m * NCH + c) * DD + k] = s;
    if (k == 0) gate_part[m * NCH + c] = g_s[0] + g_s[1] + g_s[2] + g_s[3];
  }
}

// Final per-m reduce: gate mean, delta = (Su/N)@Wu2 + bu2, mem2 = mem + gate*delta
__global__ __launch_bounds__(DD) void k_reduce(
    const float* __restrict__ gate_part, const float* __restrict__ su_part,
    const float* __restrict__ Wu2, const float* __restrict__ bu2,
    const float* __restrict__ mem_in, float* __restrict__ mem_out,
    float* __restrict__ gate_out, int N, int M, int NCH) {
  int m = blockIdx.x;
  int k = threadIdx.x;
  __shared__ float su_s[DD];
  __shared__ float gmean;
  float invN = frcp((float)N);  // N is a power of two -> exact
  float s = 0.f;
  for (int c = 0; c < NCH; c++) s += su_part[((size_t)m * NCH + c) * DD + k];
  su_s[k] = s * invN;
  if (k == 0) {
    float g = 0.f;
    for (int c = 0; c < NCH; c++) g += gate_part[m * NCH + c];
    gmean = g * invN;
  }
  __syncthreads();
  float delta = bu2[k];
#pragma unroll 8
  for (int j = 0; j < DD; j++) delta += su_s[j] * Wu2[j * DD + k];
  float gm = gmean;
  mem_out[m * DD + k] = mem_in[m * DD + k] + gm * delta;
  if (k == 0) gate_out[m] = gm;
}

extern "C" void kernel_launch(void* const* d_in, const int* in_sizes, int n_in,
                              void* d_out, int out_size, void* d_ws, size_t ws_size,
                              hipStream_t stream) {
  const float* coords = (const float*)d_in[0];
  const float* memory_slots = (const float*)d_in[1];
  const float* anchor_keys = (const float*)d_in[2];
  const float* rpos = (const float*)d_in[3];
  const float* rrad = (const float*)d_in[4];
  const float* W1 = (const float*)d_in[5];
  const float* b1 = (const float*)d_in[6];
  const float* W2 = (const float*)d_in[7];
  const float* b2 = (const float*)d_in[8];
  const float* Wg1 = (const float*)d_in[9];
  const float* bg1 = (const float*)d_in[10];
  const float* Wg2 = (const float*)d_in[11];
  const float* bg2 = (const float*)d_in[12];
  const float* Wu1 = (const float*)d_in[13];
  const float* bu1 = (const float*)d_in[14];
  const float* Wu2 = (const float*)d_in[15];
  const float* bu2 = (const float*)d_in[16];

  const int N = in_sizes[0] / 3;   // 4096
  const int M = in_sizes[1] / DD;  // 256
  const int R = in_sizes[4];       // 512
  const int NCH = N / 256;         // 16

  // d_out layout: mc[N*D] | rw[N*M] | gate[M] | sg[N] | mem[M*D]
  float* out = (float*)d_out;
  float* out_mc = out;
  float* out_rw = out_mc + (size_t)N * DD;
  float* out_gate = out_rw + (size_t)N * M;
  float* out_sg = out_gate + M;
  float* out_mem = out_sg + N;

  // workspace layout
  float* ws = (float*)d_ws;
  float* qe = ws;        ws += (size_t)N * DD;
  float* AgT4 = ws;      ws += (size_t)N * DD;
  float* Au = ws;        ws += (size_t)N * DD;
  float* keysT = ws;     ws += (size_t)DD * M;
  float* Bg = ws;        ws += (size_t)M * DD;
  float* Bu = ws;        ws += (size_t)M * DD;
  float* gate_part = ws; ws += (size_t)M * NCH;
  float* su_part = ws;   ws += (size_t)M * NCH * DD;

  k_coord<<<N, DD, 0, stream>>>(coords, W1, b1, W2, b2, qe, N);
  k_prep<<<DD, M, 0, stream>>>(anchor_keys, keysT, M);
  k_sdf<<<N / 4, 256, 0, stream>>>(rpos, rrad, coords, out_sg, N, R);

  const float* mem_cur = memory_slots;
  for (int step = 0; step < 2; step++) {
    k_attn<<<N, 256, 0, stream>>>(qe, keysT, mem_cur, out_sg, Wg1, bg1, Wu1, bu1,
                                  out_rw, out_mc, qe, AgT4, Au, N, M);
    k_b<<<M, 128, 0, stream>>>(mem_cur, Wg1, Wu1, Bg, Bu, M);
    k_write<<<dim3(M, NCH), 256, 0, stream>>>(out_rw, AgT4, Au, Bg, Bu, Wg1, Wu1,
                                              Wg2, bg2, gate_part, su_part, N, M, NCH);
    k_reduce<<<M, DD, 0, stream>>>(gate_part, su_part, Wu2, bu2, mem_cur,
                                   out_mem, out_gate, N, M, NCH);
    mem_cur = out_mem;
  }
}

// Round 4
// 146.343 us; speedup vs baseline: 2.6803x; 1.2084x over previous
//
#include <hip/hip_runtime.h>
#include <hip/hip_bf16.h>
#include <math.h>

#define DD 64

__device__ __forceinline__ float frcp(float x) { return __builtin_amdgcn_rcpf(x); }
// fast reciprocal for y >= 1 (magic + 2 Newton), rel err ~6e-6
__device__ __forceinline__ float fast_rcp_pos(float y) {
  float r = __uint_as_float(0x7EF127EAu - __float_as_uint(y));
  r = r * fmaf(-y, r, 2.0f);
  r = r * fmaf(-y, r, 2.0f);
  return r;
}
__device__ __forceinline__ float fsig(float x) {
  float e = fminf(__expf(-x), 1e30f);
  return fast_rcp_pos(1.0f + e);
}
__device__ __forceinline__ float fsilu(float x) { return x * fsig(x); }

// qe = silu(points @ W1 + b1) @ W2 + b2      [N, 64]
__global__ __launch_bounds__(DD) void k_coord(
    const float* __restrict__ coords, const float* __restrict__ W1,
    const float* __restrict__ b1, const float* __restrict__ W2,
    const float* __restrict__ b2, float* __restrict__ qe, int N) {
  int n = blockIdx.x;
  int k = threadIdx.x;
  __shared__ float h[DD];
  float px = coords[n * 3 + 0], py = coords[n * 3 + 1], pz = coords[n * 3 + 2];
  float t = px * W1[k] + py * W1[DD + k] + pz * W1[2 * DD + k] + b1[k];
  h[k] = fsilu(t);
  __syncthreads();
  float q = b2[k];
#pragma unroll 8
  for (int j = 0; j < DD; j++) q += h[j] * W2[j * DD + k];
  qe[n * DD + k] = q;
}

// keysT[j][m] = keys[m][j]
__global__ __launch_bounds__(256) void k_prep(
    const float* __restrict__ keys, float* __restrict__ keysT, int M) {
  int j = blockIdx.x;
  int t = threadIdx.x;
  keysT[j * M + t] = keys[t * DD + j];
}

// sg[n] = sigmoid(4 * min_r(|p_n - rpos_r| - rrad_r))
__global__ __launch_bounds__(256) void k_sdf(
    const float* __restrict__ rpos, const float* __restrict__ rrad,
    const float* __restrict__ coords, float* __restrict__ sg_out, int N, int R) {
  int wv = threadIdx.x >> 6, ln = threadIdx.x & 63;
  int n = blockIdx.x * 4 + wv;
  if (n >= N) return;
  float px = coords[n * 3], py = coords[n * 3 + 1], pz = coords[n * 3 + 2];
  float mn = 1e30f;
  for (int r = ln; r < R; r += 64) {
    float dx = px - rpos[r * 3], dy = py - rpos[r * 3 + 1], dz = pz - rpos[r * 3 + 2];
    float d = sqrtf(dx * dx + dy * dy + dz * dz) - rrad[r];
    mn = fminf(mn, d);
  }
  mn = fminf(mn, __shfl_xor(mn, 32, 64));
  mn = fminf(mn, __shfl_xor(mn, 16, 64));
  mn = fminf(mn, __shfl_xor(mn, 8, 64));
  mn = fminf(mn, __shfl_xor(mn, 4, 64));
  mn = fminf(mn, __shfl_xor(mn, 2, 64));
  mn = fminf(mn, __shfl_xor(mn, 1, 64));
  if (ln == 0) sg_out[n] = fsig(4.0f * mn);
}

// 4 n's per block: logits -> softmax -> rw ; mc = rw@mem ; qe += 0.5*mc ; A-proj.
__global__ __launch_bounds__(256) void k_attn(
    const float* __restrict__ qe_in, const float* __restrict__ keysT,
    const float* __restrict__ mem, const float* __restrict__ sg,
    const float* __restrict__ Wg1, const float* __restrict__ bg1,
    const float* __restrict__ Wu1, const float* __restrict__ bu1,
    float* __restrict__ rw_out, float* __restrict__ mc_out,
    float* __restrict__ qe_io, float* __restrict__ AgT4,
    float* __restrict__ Au, int N, int M) {
  int n0 = blockIdx.x * 4;
  int t = threadIdx.x;  // t == m, M == 256
  int wv = t >> 6, ln = t & 63;
  __shared__ __align__(16) float rws[4][256];
  __shared__ __align__(16) float mcs[4][DD];
  __shared__ float red[4][4], red2[4][4];
  __shared__ float part[4][4][DD];
  float lg[4] = {0.f, 0.f, 0.f, 0.f};
#pragma unroll 8
  for (int j = 0; j < DD; j++) {
    float kv = keysT[j * M + t];
    lg[0] += qe_in[(size_t)(n0 + 0) * DD + j] * kv;  // uniform -> s_load
    lg[1] += qe_in[(size_t)(n0 + 1) * DD + j] * kv;
    lg[2] += qe_in[(size_t)(n0 + 2) * DD + j] * kv;
    lg[3] += qe_in[(size_t)(n0 + 3) * DD + j] * kv;
  }
  float e[4];
#pragma unroll
  for (int q = 0; q < 4; q++) {
    float x = lg[q] * 0.125f;
    lg[q] = x;
    float mx = x;
    mx = fmaxf(mx, __shfl_xor(mx, 32, 64));
    mx = fmaxf(mx, __shfl_xor(mx, 16, 64));
    mx = fmaxf(mx, __shfl_xor(mx, 8, 64));
    mx = fmaxf(mx, __shfl_xor(mx, 4, 64));
    mx = fmaxf(mx, __shfl_xor(mx, 2, 64));
    mx = fmaxf(mx, __shfl_xor(mx, 1, 64));
    if (ln == 0) red[q][wv] = mx;
  }
  __syncthreads();
#pragma unroll
  for (int q = 0; q < 4; q++) {
    float mx = fmaxf(fmaxf(red[q][0], red[q][1]), fmaxf(red[q][2], red[q][3]));
    float ee = __expf(lg[q] - mx);
    e[q] = ee;
    float sm = ee;
    sm += __shfl_xor(sm, 32, 64);
    sm += __shfl_xor(sm, 16, 64);
    sm += __shfl_xor(sm, 8, 64);
    sm += __shfl_xor(sm, 4, 64);
    sm += __shfl_xor(sm, 2, 64);
    sm += __shfl_xor(sm, 1, 64);
    if (ln == 0) red2[q][wv] = sm;
  }
  __syncthreads();
#pragma unroll
  for (int q = 0; q < 4; q++) {
    float tot = red2[q][0] + red2[q][1] + red2[q][2] + red2[q][3];
    float rv = e[q] * frcp(tot);
    rw_out[(size_t)(n0 + q) * M + t] = rv;
    rws[q][t] = rv;
  }
  __syncthreads();
  // mc: wave wv covers m in [wv*64, wv*64+64), k = ln
  float acc[4] = {0.f, 0.f, 0.f, 0.f};
#pragma unroll
  for (int mm4 = 0; mm4 < 16; mm4++) {
    int mbase = wv * 64 + mm4 * 4;
    const float4 r0 = *reinterpret_cast<const float4*>(&rws[0][mbase]);
    const float4 r1 = *reinterpret_cast<const float4*>(&rws[1][mbase]);
    const float4 r2 = *reinterpret_cast<const float4*>(&rws[2][mbase]);
    const float4 r3 = *reinterpret_cast<const float4*>(&rws[3][mbase]);
    float m0v = mem[(size_t)(mbase + 0) * DD + ln];
    float m1v = mem[(size_t)(mbase + 1) * DD + ln];
    float m2v = mem[(size_t)(mbase + 2) * DD + ln];
    float m3v = mem[(size_t)(mbase + 3) * DD + ln];
    acc[0] += r0.x * m0v + r0.y * m1v + r0.z * m2v + r0.w * m3v;
    acc[1] += r1.x * m0v + r1.y * m1v + r1.z * m2v + r1.w * m3v;
    acc[2] += r2.x * m0v + r2.y * m1v + r2.z * m2v + r2.w * m3v;
    acc[3] += r3.x * m0v + r3.y * m1v + r3.z * m2v + r3.w * m3v;
  }
#pragma unroll
  for (int q = 0; q < 4; q++) part[q][wv][ln] = acc[q];
  __syncthreads();
  // mc finalize: wave q handles n0+q
  {
    int q = wv;
    float mc = part[q][0][ln] + part[q][1][ln] + part[q][2][ln] + part[q][3][ln];
    mc_out[(size_t)(n0 + q) * DD + ln] = mc;
    qe_io[(size_t)(n0 + q) * DD + ln] =
        qe_in[(size_t)(n0 + q) * DD + ln] + 0.5f * mc;
    mcs[q][ln] = mc;
  }
  __syncthreads();
  // A-proj: wv0:(g,n0,n1) wv1:(g,n2,n3) wv2:(u,n0,n1) wv3:(u,n2,n3)
  {
    const float* W = (wv < 2) ? Wg1 : Wu1;
    const float* bb = (wv < 2) ? bg1 : bu1;
    int qa = (wv & 1) * 2, qb = qa + 1;
    int k = ln;
    float w129 = W[129 * DD + k];
    float bbk = bb[k];
    float a0 = bbk + sg[n0 + qa] * w129;
    float a1 = bbk + sg[n0 + qb] * w129;
#pragma unroll
    for (int j4 = 0; j4 < 16; j4++) {
      const float4 ma = *reinterpret_cast<const float4*>(&mcs[qa][j4 * 4]);
      const float4 mb = *reinterpret_cast<const float4*>(&mcs[qb][j4 * 4]);
      float w0 = W[(size_t)(j4 * 4 + 0) * DD + k];
      float w1 = W[(size_t)(j4 * 4 + 1) * DD + k];
      float w2v = W[(size_t)(j4 * 4 + 2) * DD + k];
      float w3 = W[(size_t)(j4 * 4 + 3) * DD + k];
      a0 += ma.x * w0 + ma.y * w1 + ma.z * w2v + ma.w * w3;
      a1 += mb.x * w0 + mb.y * w1 + mb.z * w2v + mb.w * w3;
    }
    if (wv < 2) {
      AgT4[((size_t)(k >> 2) * N + n0 + qa) * 4 + (k & 3)] = a0;
      AgT4[((size_t)(k >> 2) * N + n0 + qb) * 4 + (k & 3)] = a1;
    } else {
      Au[(size_t)(n0 + qa) * DD + k] = a0;
      Au[(size_t)(n0 + qb) * DD + k] = a1;
    }
  }
}

// initial Bg/Bu from memory_slots
__global__ __launch_bounds__(128) void k_b(
    const float* __restrict__ mem, const float* __restrict__ Wg1,
    const float* __restrict__ Wu1, float* __restrict__ Bg,
    float* __restrict__ Bu, int M) {
  int m = blockIdx.x;
  int t = threadIdx.x;
  __shared__ float row[DD];
  if (t < DD) row[t] = mem[m * DD + t];
  __syncthreads();
  int k = t & 63;
  const float* W = (t < DD) ? Wg1 : Wu1;
  float b = 0.f;
#pragma unroll 8
  for (int j = 0; j < DD; j++) b += row[j] * W[(DD + j) * DD + k];
  if (t < DD) Bg[m * DD + k] = b;
  else Bu[m * DD + k] = b;
}

// Main pair loop. 1D grid; block = (m-pair, chunk). 2 m's per block.
__global__ __launch_bounds__(256) void k_write(
    const float* __restrict__ rw, const float* __restrict__ AgT4,
    const float* __restrict__ Au, const float* __restrict__ Bg,
    const float* __restrict__ Bu, const float* __restrict__ Wg1,
    const float* __restrict__ Wu1, const float* __restrict__ Wg2,
    const float* __restrict__ bg2, float* __restrict__ gate_part,
    float* __restrict__ su_part, int N, int M, int NCH) {
  int bx = blockIdx.x;
  int c = bx % NCH;            // XCD = bx%8 = c%8 -> each XCD owns 2 chunks
  int m0 = (bx / NCH) * 2;
  int wave = threadIdx.x >> 6, lane = threadIdx.x & 63;
  int n0 = __builtin_amdgcn_readfirstlane(c * 256 + wave * 64);
  const float* Wg1r = Wg1 + 128 * DD;

  // ---- path G: lane = n offset ----
  float rwl0 = rw[(size_t)(n0 + lane) * M + m0];
  float rwl1 = rw[(size_t)(n0 + lane) * M + m0 + 1];
  float g0a = 0.f, g0b = 0.f, g1a = 0.f, g1b = 0.f;
#pragma unroll
  for (int k4 = 0; k4 < 16; k4++) {
    const float4 ag4 = *reinterpret_cast<const float4*>(
        &AgT4[((size_t)k4 * N + n0 + lane) * 4]);
    {
      int k = k4 * 4 + 0;
      float bA = Bg[m0 * DD + k], bB = Bg[m0 * DD + DD + k];
      float wr = Wg1r[k], w2 = Wg2[k];
      g0a += fsilu(ag4.x + bA + rwl0 * wr) * w2;
      g1a += fsilu(ag4.x + bB + rwl1 * wr) * w2;
    }
    {
      int k = k4 * 4 + 1;
      float bA = Bg[m0 * DD + k], bB = Bg[m0 * DD + DD + k];
      float wr = Wg1r[k], w2 = Wg2[k];
      g0b += fsilu(ag4.y + bA + rwl0 * wr) * w2;
      g1b += fsilu(ag4.y + bB + rwl1 * wr) * w2;
    }
    {
      int k = k4 * 4 + 2;
      float bA = Bg[m0 * DD + k], bB = Bg[m0 * DD + DD + k];
      float wr = Wg1r[k], w2 = Wg2[k];
      g0a += fsilu(ag4.z + bA + rwl0 * wr) * w2;
      g1a += fsilu(ag4.z + bB + rwl1 * wr) * w2;
    }
    {
      int k = k4 * 4 + 3;
      float bA = Bg[m0 * DD + k], bB = Bg[m0 * DD + DD + k];
      float wr = Wg1r[k], w2 = Wg2[k];
      g0b += fsilu(ag4.w + bA + rwl0 * wr) * w2;
      g1b += fsilu(ag4.w + bB + rwl1 * wr) * w2;
    }
  }
  float bg2v = bg2[0];
  float gate0 = fsig(g0a + g0b + bg2v);
  float gate1 = fsig(g1a + g1b + bg2v);
  gate0 += __shfl_xor(gate0, 32, 64);
  gate0 += __shfl_xor(gate0, 16, 64);
  gate0 += __shfl_xor(gate0, 8, 64);
  gate0 += __shfl_xor(gate0, 4, 64);
  gate0 += __shfl_xor(gate0, 2, 64);
  gate0 += __shfl_xor(gate0, 1, 64);
  gate1 += __shfl_xor(gate1, 32, 64);
  gate1 += __shfl_xor(gate1, 16, 64);
  gate1 += __shfl_xor(gate1, 8, 64);
  gate1 += __shfl_xor(gate1, 4, 64);
  gate1 += __shfl_xor(gate1, 2, 64);
  gate1 += __shfl_xor(gate1, 1, 64);

  // ---- path U: lane = k ----
  float bu0 = Bu[m0 * DD + lane], bu1v = Bu[m0 * DD + DD + lane];
  float wu1r = Wu1[128 * DD + lane];
  float s0a = 0.f, s0b = 0.f, s1a = 0.f, s1b = 0.f;
  const float* Aup = Au + (size_t)n0 * DD + lane;
  const float* rwp = rw + (size_t)n0 * M + m0;
#pragma unroll 8
  for (int i = 0; i < 64; i++) {
    float rv0 = rwp[(size_t)i * M];      // uniform -> s_load
    float rv1 = rwp[(size_t)i * M + 1];
    float au = Aup[(size_t)i * DD];
    float v0 = fsilu(au + bu0 + rv0 * wu1r);
    float v1 = fsilu(au + bu1v + rv1 * wu1r);
    if (i & 1) { s0b += v0; s1b += v1; } else { s0a += v0; s1a += v1; }
  }
  float su0 = s0a + s0b, su1 = s1a + s1b;

  __shared__ float su_s[4][2][DD];
  __shared__ float g_s[4][2];
  su_s[wave][0][lane] = su0;
  su_s[wave][1][lane] = su1;
  if (lane == 0) { g_s[wave][0] = gate0; g_s[wave][1] = gate1; }
  __syncthreads();
  if (threadIdx.x < 128) {
    int mi = threadIdx.x >> 6;
    int k = threadIdx.x & 63;
    float s = su_s[0][mi][k] + su_s[1][mi][k] + su_s[2][mi][k] + su_s[3][mi][k];
    su_part[((size_t)(m0 + mi) * NCH + c) * DD + k] = s;
    if (k == 0)
      gate_part[(m0 + mi) * NCH + c] =
          g_s[0][mi] + g_s[1][mi] + g_s[2][mi] + g_s[3][mi];
  }
}

// per-m: gate mean, delta, mem2 ; then Bg/Bu for next step from mem2
__global__ __launch_bounds__(128) void k_reduce_b(
    const float* __restrict__ gate_part, const float* __restrict__ su_part,
    const float* __restrict__ Wu2, const float* __restrict__ bu2,
    const float* __restrict__ mem_in, const float* __restrict__ Wg1,
    const float* __restrict__ Wu1, float* __restrict__ mem_out,
    float* __restrict__ gate_out, float* __restrict__ Bg,
    float* __restrict__ Bu, int N, int M, int NCH) {
  int m = blockIdx.x;
  int t = threadIdx.x;
  int k = t & 63;
  __shared__ float su_s[DD];
  __shared__ float row[DD];
  __shared__ float gmean;
  float invN = frcp((float)N);  // N pow2 -> exact
  if (t < DD) {
    float s = 0.f;
    for (int c = 0; c < NCH; c++) s += su_part[((size_t)m * NCH + c) * DD + k];
    su_s[k] = s * invN;
    if (k == 0) {
      float g = 0.f;
      for (int c = 0; c < NCH; c++) g += gate_part[m * NCH + c];
      gmean = g * invN;
    }
  }
  __syncthreads();
  if (t < DD) {
    float delta = bu2[k];
#pragma unroll 8
    for (int j = 0; j < DD; j++) delta += su_s[j] * Wu2[j * DD + k];
    float v = mem_in[m * DD + k] + gmean * delta;
    mem_out[m * DD + k] = v;
    row[k] = v;
    if (k == 0) gate_out[m] = gmean;
  }
  __syncthreads();
  const float* W = (t < DD) ? Wg1 : Wu1;
  float b = 0.f;
#pragma unroll 8
  for (int j = 0; j < DD; j++) b += row[j] * W[(DD + j) * DD + k];
  if (t < DD) Bg[m * DD + k] = b;
  else Bu[m * DD + k] = b;
}

extern "C" void kernel_launch(void* const* d_in, const int* in_sizes, int n_in,
                              void* d_out, int out_size, void* d_ws, size_t ws_size,
                              hipStream_t stream) {
  const float* coords = (const float*)d_in[0];
  const float* memory_slots = (const float*)d_in[1];
  const float* anchor_keys = (const float*)d_in[2];
  const float* rpos = (const float*)d_in[3];
  const float* rrad = (const float*)d_in[4];
  const float* W1 = (const float*)d_in[5];
  const float* b1 = (const float*)d_in[6];
  const float* W2 = (const float*)d_in[7];
  const float* b2 = (const float*)d_in[8];
  const float* Wg1 = (const float*)d_in[9];
  const float* bg1 = (const float*)d_in[10];
  const float* Wg2 = (const float*)d_in[11];
  const float* bg2 = (const float*)d_in[12];
  const float* Wu1 = (const float*)d_in[13];
  const float* bu1 = (const float*)d_in[14];
  const float* Wu2 = (const float*)d_in[15];
  const float* bu2 = (const float*)d_in[16];

  const int N = in_sizes[0] / 3;   // 4096
  const int M = in_sizes[1] / DD;  // 256
  const int R = in_sizes[4];       // 512
  const int NCH = N / 256;         // 16

  // d_out layout: mc[N*D] | rw[N*M] | gate[M] | sg[N] | mem[M*D]
  float* out = (float*)d_out;
  float* out_mc = out;
  float* out_rw = out_mc + (size_t)N * DD;
  float* out_gate = out_rw + (size_t)N * M;
  float* out_sg = out_gate + M;
  float* out_mem = out_sg + N;

  // workspace layout
  float* ws = (float*)d_ws;
  float* qe = ws;        ws += (size_t)N * DD;
  float* AgT4 = ws;      ws += (size_t)N * DD;
  float* Au = ws;        ws += (size_t)N * DD;
  float* keysT = ws;     ws += (size_t)DD * M;
  float* Bg = ws;        ws += (size_t)M * DD;
  float* Bu = ws;        ws += (size_t)M * DD;
  float* gate_part = ws; ws += (size_t)M * NCH;
  float* su_part = ws;   ws += (size_t)M * NCH * DD;

  k_coord<<<N, DD, 0, stream>>>(coords, W1, b1, W2, b2, qe, N);
  k_prep<<<DD, M, 0, stream>>>(anchor_keys, keysT, M);
  k_sdf<<<N / 4, 256, 0, stream>>>(rpos, rrad, coords, out_sg, N, R);
  k_b<<<M, 128, 0, stream>>>(memory_slots, Wg1, Wu1, Bg, Bu, M);

  const float* mem_cur = memory_slots;
  for (int step = 0; step < 2; step++) {
    k_attn<<<N / 4, 256, 0, stream>>>(qe, keysT, mem_cur, out_sg, Wg1, bg1, Wu1,
                                      bu1, out_rw, out_mc, qe, AgT4, Au, N, M);
    k_write<<<(M / 2) * NCH, 256, 0, stream>>>(out_rw, AgT4, Au, Bg, Bu, Wg1,
                                               Wu1, Wg2, bg2, gate_part, su_part,
                                               N, M, NCH);
    k_reduce_b<<<M, 128, 0, stream>>>(gate_part, su_part, Wu2, bu2, mem_cur,
                                      Wg1, Wu1, out_mem, out_gate, Bg, Bu,
                                      N, M, NCH);
    mem_cur = out_mem;
  }
}